// Round 1
// baseline (466.265 us; speedup 1.0000x reference)
//
#include <hip/hip_runtime.h>

#define TILE 64
#define BK   16

// Generic fp32 tiled GEMM.
//  C[m,n] = sum_k A[m,k] * (BT ? B[n,k] : B[k,n])  (+ bias[n]) (relu)
// A: [M,K] row-major. B: BT ? [N,K] : [K,N]. C: [M,N].
// blockIdx.z batches with strides sA/sB/sC (in elements).
// Requires M%64==0, N%64==0, K%16==0, K%4==0, N%4==0 (all true here).
template<bool BT, bool BIAS, bool RELU>
__global__ __launch_bounds__(256)
void gemm_kernel(const float* __restrict__ A, const float* __restrict__ B,
                 const float* __restrict__ bias, float* __restrict__ C,
                 int M, int N, int K, long sA, long sB, long sC)
{
    (void)M;
    __shared__ float As[BK][TILE + 4];  // k-major, pad 4 -> row stride 272B (16B aligned)
    __shared__ float Bs[BK][TILE + 4];

    const int bz = blockIdx.z;
    A += (long)bz * sA;
    B += (long)bz * sB;
    C += (long)bz * sC;

    const int m0 = blockIdx.y * TILE;
    const int n0 = blockIdx.x * TILE;
    const int tid = threadIdx.x;
    const int tx = tid & 15;          // output col group
    const int ty = tid >> 4;          // output row group

    // staging indices: 64 rows x 16 k, one float4 (along k) per thread
    const int arow = tid >> 2;        // 0..63
    const int akq  = (tid & 3) << 2;  // 0,4,8,12
    // NN staging: 16 k-rows x 64 n-cols, one float4 (along n) per thread
    const int bkr = tid >> 4;         // 0..15
    const int bnc = (tid & 15) << 2;  // 0..60

    float acc[4][4] = {};

    for (int k0 = 0; k0 < K; k0 += BK) {
        float4 av = *reinterpret_cast<const float4*>(&A[(long)(m0 + arow) * K + (k0 + akq)]);
        As[akq + 0][arow] = av.x;
        As[akq + 1][arow] = av.y;
        As[akq + 2][arow] = av.z;
        As[akq + 3][arow] = av.w;
        if (BT) {
            float4 bv = *reinterpret_cast<const float4*>(&B[(long)(n0 + arow) * K + (k0 + akq)]);
            Bs[akq + 0][arow] = bv.x;
            Bs[akq + 1][arow] = bv.y;
            Bs[akq + 2][arow] = bv.z;
            Bs[akq + 3][arow] = bv.w;
        } else {
            float4 bv = *reinterpret_cast<const float4*>(&B[(long)(k0 + bkr) * N + (n0 + bnc)]);
            *reinterpret_cast<float4*>(&Bs[bkr][bnc]) = bv;
        }
        __syncthreads();
#pragma unroll
        for (int kk = 0; kk < BK; ++kk) {
            float4 a  = *reinterpret_cast<const float4*>(&As[kk][ty << 2]);
            float4 bb = *reinterpret_cast<const float4*>(&Bs[kk][tx << 2]);
            float ar[4] = {a.x, a.y, a.z, a.w};
            float br[4] = {bb.x, bb.y, bb.z, bb.w};
#pragma unroll
            for (int i = 0; i < 4; ++i)
#pragma unroll
                for (int j = 0; j < 4; ++j)
                    acc[i][j] = fmaf(ar[i], br[j], acc[i][j]);
        }
        __syncthreads();
    }

    float4 bv4 = make_float4(0.f, 0.f, 0.f, 0.f);
    if (BIAS) bv4 = *reinterpret_cast<const float4*>(&bias[n0 + (tx << 2)]);
#pragma unroll
    for (int i = 0; i < 4; ++i) {
        float4 v;
        v.x = acc[i][0]; v.y = acc[i][1]; v.z = acc[i][2]; v.w = acc[i][3];
        if (BIAS) { v.x += bv4.x; v.y += bv4.y; v.z += bv4.z; v.w += bv4.w; }
        if (RELU) {
            v.x = fmaxf(v.x, 0.f); v.y = fmaxf(v.y, 0.f);
            v.z = fmaxf(v.z, 0.f); v.w = fmaxf(v.w, 0.f);
        }
        *reinterpret_cast<float4*>(&C[(long)(m0 + (ty << 2) + i) * N + n0 + (tx << 2)]) = v;
    }
}

// MedLane masked softmax over the last axis (length 512), literal transcription:
//   s = att * mask; M = max(s); e = exp(s - M); Z = sum(e);
//   p = (e/Z) * mask; S = sum(p); out = p / (S + 1e-13)
// One 256-thread block per (b,p) row; 2 elements per thread.
__global__ __launch_bounds__(256)
void softmax_kernel(float* __restrict__ att, const int* __restrict__ seq_len)
{
    const int row = blockIdx.x;         // b*512 + p
    const int b   = row >> 9;
    float* s = att + (long)row * 512;
    const int L = seq_len[b];
    const int tid = threadIdx.x;

    __shared__ float red[4];

    float v0 = s[tid];
    float v1 = s[tid + 256];
    float s0 = (tid < L) ? v0 : 0.0f;
    float s1 = (tid + 256 < L) ? v1 : 0.0f;

    // block max
    float m = fmaxf(s0, s1);
#pragma unroll
    for (int o = 32; o > 0; o >>= 1) m = fmaxf(m, __shfl_down(m, o));
    if ((tid & 63) == 0) red[tid >> 6] = m;
    __syncthreads();
    const float M = fmaxf(fmaxf(red[0], red[1]), fmaxf(red[2], red[3]));
    __syncthreads();

    const float e0 = expf(s0 - M);
    const float e1 = expf(s1 - M);

    // block sum of all exps
    float z = e0 + e1;
#pragma unroll
    for (int o = 32; o > 0; o >>= 1) z += __shfl_down(z, o);
    if ((tid & 63) == 0) red[tid >> 6] = z;
    __syncthreads();
    const float Z = red[0] + red[1] + red[2] + red[3];
    __syncthreads();

    const float p0 = (tid < L)       ? e0 / Z : 0.0f;
    const float p1 = (tid + 256 < L) ? e1 / Z : 0.0f;

    // block sum of masked probs
    float ss = p0 + p1;
#pragma unroll
    for (int o = 32; o > 0; o >>= 1) ss += __shfl_down(ss, o);
    if ((tid & 63) == 0) red[tid >> 6] = ss;
    __syncthreads();
    const float S = red[0] + red[1] + red[2] + red[3];

    const float inv = 1.0f / (S + 1e-13f);
    s[tid]       = p0 * inv;
    s[tid + 256] = p1 * inv;
}

extern "C" void kernel_launch(void* const* d_in, const int* in_sizes, int n_in,
                              void* d_out, int out_size, void* d_ws, size_t ws_size,
                              hipStream_t stream)
{
    (void)in_sizes; (void)n_in; (void)out_size; (void)ws_size;

    constexpr int B = 16, LP = 512, LQ = 512, H = 768;

    const float* proj_p  = (const float*)d_in[0];   // [B, LP, H]
    const float* proj_q  = (const float*)d_in[1];   // [B, LQ, H]
    const int*   seq_len = (const int*)d_in[2];     // [B]
    const float* W       = (const float*)d_in[3];   // [H, H]  (o, h)
    const float* bias    = (const float*)d_in[4];   // [H]
    float* out = (float*)d_out;                     // [B, LP, H]

    // workspace layout (floats): 64 MB total
    float* trans_q = (float*)d_ws;                          // B*LQ*H = 6291456
    float* att     = trans_q + (size_t)B * LQ * H;          // B*LP*LQ = 4194304
    float* att_vec = att + (size_t)B * LP * LQ;             // B*LP*H = 6291456

    dim3 blk(256);

    // 1) trans_q = proj_q @ W^T + bias   [8192,768] x [768,768]^T
    gemm_kernel<true, true, false><<<dim3(H / TILE, (B * LQ) / TILE, 1), blk, 0, stream>>>(
        proj_q, W, bias, trans_q, B * LQ, H, H, 0, 0, 0);

    // 2) att[b] = proj_p[b] @ trans_q[b]^T   per-batch [512,768] x [512,768]^T
    gemm_kernel<true, false, false><<<dim3(LQ / TILE, LP / TILE, B), blk, 0, stream>>>(
        proj_p, trans_q, nullptr, att, LP, LQ, H,
        (long)LP * H, (long)LQ * H, (long)LP * LQ);

    // 3) masked softmax (in place over att)
    softmax_kernel<<<B * LP, 256, 0, stream>>>(att, seq_len);

    // 4) att_vec[b] = probs[b] @ proj_q[b]   per-batch [512,512] x [512,768]
    gemm_kernel<false, false, false><<<dim3(H / TILE, LP / TILE, B), blk, 0, stream>>>(
        att, proj_q, nullptr, att_vec, LP, H, LQ,
        (long)LP * LQ, (long)LQ * H, (long)LP * H);

    // 5) out = relu(att_vec @ W^T + bias)   [8192,768] x [768,768]^T
    gemm_kernel<true, true, true><<<dim3(H / TILE, (B * LP) / TILE, 1), blk, 0, stream>>>(
        att_vec, W, bias, out, B * LP, H, H, 0, 0, 0);
}

// Round 2
// 176.251 us; speedup vs baseline: 2.6455x; 2.6455x over previous
//
#include <hip/hip_runtime.h>

typedef __attribute__((ext_vector_type(8))) short short8;
typedef __attribute__((ext_vector_type(4))) float f32x4;
typedef unsigned short u16;

__device__ __forceinline__ u16 f2bf(float f) {
    unsigned u = __builtin_bit_cast(unsigned, f);
    u += 0x7fffu + ((u >> 16) & 1u);
    return (u16)(u >> 16);
}
__device__ __forceinline__ float bf2f(u16 h) {
    return __builtin_bit_cast(float, (unsigned)h << 16);
}

// async global->LDS, 16B per lane; LDS dest = wave-uniform base + lane*16
#define GLDS(G, LBYTE)                                                         \
    __builtin_amdgcn_global_load_lds(                                          \
        (const __attribute__((address_space(1))) void*)(G),                    \
        (__attribute__((address_space(3))) void*)((char*)lds + (LBYTE)),       \
        16, 0, 0)

// NT GEMM: C[m,n] = sum_k A[m,k]*B[n,k]  (A:[M,K] bf16(+lo), B:[N,K] bf16(+lo))
// 128x128 tile, BK=32, 256 threads (4 waves, each 64x64 via 4x4 mfma 16x16x32).
// SPLIT: A,B given as hi+lo bf16 planes, 3 MFMAs (hi*hi + hi*lo + lo*hi).
// OUT: 0 = fp32, 1 = bf16, 2 = bf16 hi+lo pair (Cv=hi plane, C2=lo plane).
template<bool SPLIT, int OUT, bool BIAS, bool RELU>
__global__ __launch_bounds__(256, 2)
void gemm_nt(const u16* __restrict__ Ah, const u16* __restrict__ Al,
             const u16* __restrict__ Bh, const u16* __restrict__ Bl,
             const float* __restrict__ bias,
             void* __restrict__ Cv, u16* __restrict__ C2,
             int K, int lda, int ldb, int ldc,
             long sA, long sB, long sC)
{
    __shared__ u16 lds[SPLIT ? 16384 : 8192];
    const int tid  = threadIdx.x;
    const int lane = tid & 63;
    const int wid  = tid >> 6;
    const int z  = blockIdx.z;
    const int m0 = blockIdx.y * 128;
    const int n0 = blockIdx.x * 128;

    // staging map: thread t -> tile row t>>2 (+64 for 2nd chunk), col (t&3)*8
    const size_t srow = (size_t)(tid >> 2);
    const int    scol = (tid & 3) * 8;
    const unsigned ldsW = (unsigned)wid * 1024u;   // per-wave 1KB within 4KB chunk

    const u16* aH = Ah + (size_t)z * sA + ((size_t)m0 + srow) * lda + scol;
    const u16* bH = Bh + (size_t)z * sB + ((size_t)n0 + srow) * ldb + scol;
    const u16* aL = SPLIT ? (Al + (size_t)z * sA + ((size_t)m0 + srow) * lda + scol) : nullptr;
    const u16* bL = SPLIT ? (Bl + (size_t)z * sB + ((size_t)n0 + srow) * ldb + scol) : nullptr;

    const int wm  = (wid & 1) * 64;       // wave row in tile
    const int wn  = (wid >> 1) * 64;      // wave col in tile
    const int fr  = lane & 15;
    const int fco = (lane >> 4) * 8;

    f32x4 acc[4][4] = {};

    for (int k0 = 0; k0 < K; k0 += 32) {
        GLDS(aH + k0,                 0 + ldsW);
        GLDS(aH + k0 + 64 * lda,   4096 + ldsW);
        GLDS(bH + k0,              8192 + ldsW);
        GLDS(bH + k0 + 64 * ldb,  12288 + ldsW);
        if (SPLIT) {
            GLDS(aL + k0,             16384 + ldsW);
            GLDS(aL + k0 + 64 * lda,  20480 + ldsW);
            GLDS(bL + k0,             24576 + ldsW);
            GLDS(bL + k0 + 64 * ldb,  28672 + ldsW);
        }
        __syncthreads();

        short8 vah[4], vbh[4];
#pragma unroll
        for (int i = 0; i < 4; ++i) {
            vah[i] = *(const short8*)(lds +        (wm + i * 16 + fr) * 32 + fco);
            vbh[i] = *(const short8*)(lds + 4096 + (wn + i * 16 + fr) * 32 + fco);
        }
#pragma unroll
        for (int i = 0; i < 4; ++i)
#pragma unroll
            for (int j = 0; j < 4; ++j)
                acc[i][j] = __builtin_amdgcn_mfma_f32_16x16x32_bf16(vah[i], vbh[j], acc[i][j], 0, 0, 0);

        if (SPLIT) {
            short8 val[4], vbl[4];
#pragma unroll
            for (int i = 0; i < 4; ++i) {
                val[i] = *(const short8*)(lds +  8192 + (wm + i * 16 + fr) * 32 + fco);
                vbl[i] = *(const short8*)(lds + 12288 + (wn + i * 16 + fr) * 32 + fco);
            }
#pragma unroll
            for (int i = 0; i < 4; ++i)
#pragma unroll
                for (int j = 0; j < 4; ++j) {
                    acc[i][j] = __builtin_amdgcn_mfma_f32_16x16x32_bf16(vah[i], vbl[j], acc[i][j], 0, 0, 0);
                    acc[i][j] = __builtin_amdgcn_mfma_f32_16x16x32_bf16(val[i], vbh[j], acc[i][j], 0, 0, 0);
                }
        }
        __syncthreads();
    }

    float bj[4];
    if (BIAS) {
#pragma unroll
        for (int j = 0; j < 4; ++j) bj[j] = bias[n0 + wn + j * 16 + fr];
    }
    const long crow0 = m0 + wm + (lane >> 4) * 4;
    const long ccol0 = n0 + wn + fr;
    float* Cf = (float*)Cv + (size_t)z * sC;
    u16*   Cb = (u16*)Cv   + (size_t)z * sC;
    u16*   Cl = (OUT == 2) ? (C2 + (size_t)z * sC) : nullptr;
#pragma unroll
    for (int i = 0; i < 4; ++i)
#pragma unroll
        for (int j = 0; j < 4; ++j)
#pragma unroll
            for (int r = 0; r < 4; ++r) {
                float v = acc[i][j][r];
                if (BIAS) v += bj[j];
                if (RELU) v = fmaxf(v, 0.0f);
                const size_t idx = (size_t)(crow0 + i * 16 + r) * ldc + ccol0 + j * 16;
                if (OUT == 0) Cf[idx] = v;
                else if (OUT == 1) Cb[idx] = f2bf(v);
                else {
                    u16 h = f2bf(v);
                    Cb[idx] = h;
                    Cl[idx] = f2bf(v - bf2f(h));
                }
            }
}

// fp32 -> (hi bf16, lo bf16) planes, vectorized
__global__ __launch_bounds__(256)
void split_f32(const float* __restrict__ x, u16* __restrict__ hi,
               u16* __restrict__ lo, int n4)
{
    int i = blockIdx.x * 256 + threadIdx.x;
    const int stride = gridDim.x * 256;
    for (; i < n4; i += stride) {
        float4 v = ((const float4*)x)[i];
        ushort4 h, l;
        h.x = f2bf(v.x); l.x = f2bf(v.x - bf2f(h.x));
        h.y = f2bf(v.y); l.y = f2bf(v.y - bf2f(h.y));
        h.z = f2bf(v.z); l.z = f2bf(v.z - bf2f(h.z));
        h.w = f2bf(v.w); l.w = f2bf(v.w - bf2f(h.w));
        ((ushort4*)hi)[i] = h;
        ((ushort4*)lo)[i] = l;
    }
}

// per-batch transpose [512,768] fp32 -> [768,512] bf16
__global__ __launch_bounds__(256)
void transpose_to_bf16(const float* __restrict__ src, u16* __restrict__ dst)
{
    __shared__ u16 t[32][33];
    const int z = blockIdx.z;
    src += (size_t)z * 512 * 768;
    dst += (size_t)z * 768 * 512;
    const int h0 = blockIdx.x * 32;
    const int q0 = blockIdx.y * 32;
    const int tx = threadIdx.x;   // 0..31
    const int ty = threadIdx.y;   // 0..7
#pragma unroll
    for (int r = 0; r < 4; ++r)
        t[ty * 4 + r][tx] = f2bf(src[(size_t)(q0 + ty * 4 + r) * 768 + h0 + tx]);
    __syncthreads();
#pragma unroll
    for (int r = 0; r < 4; ++r)
        dst[(size_t)(h0 + ty * 4 + r) * 512 + q0 + tx] = t[tx][ty * 4 + r];
}

// MedLane masked softmax over 512 (fp32 in), writes bf16 probs in place
// (row stride stays 512 floats = 1024 bf16 elements)
__global__ __launch_bounds__(256)
void softmax_kernel(float* __restrict__ att, const int* __restrict__ seq_len)
{
    const int row = blockIdx.x;
    const int b   = row >> 9;
    float* s = att + (size_t)row * 512;
    const int L = seq_len[b];
    const int tid = threadIdx.x;

    __shared__ float red[4];

    const float v0 = s[tid];
    const float v1 = s[tid + 256];
    const float s0 = (tid < L) ? v0 : 0.0f;
    const float s1 = (tid + 256 < L) ? v1 : 0.0f;

    float m = fmaxf(s0, s1);
#pragma unroll
    for (int o = 32; o > 0; o >>= 1) m = fmaxf(m, __shfl_down(m, o));
    if ((tid & 63) == 0) red[tid >> 6] = m;
    __syncthreads();
    const float M = fmaxf(fmaxf(red[0], red[1]), fmaxf(red[2], red[3]));
    __syncthreads();

    const float e0 = expf(s0 - M);
    const float e1 = expf(s1 - M);

    float zs = e0 + e1;
#pragma unroll
    for (int o = 32; o > 0; o >>= 1) zs += __shfl_down(zs, o);
    if ((tid & 63) == 0) red[tid >> 6] = zs;
    __syncthreads();
    const float Z = red[0] + red[1] + red[2] + red[3];
    __syncthreads();

    const float p0 = (tid < L)       ? e0 / Z : 0.0f;
    const float p1 = (tid + 256 < L) ? e1 / Z : 0.0f;

    float ss = p0 + p1;
#pragma unroll
    for (int o = 32; o > 0; o >>= 1) ss += __shfl_down(ss, o);
    if ((tid & 63) == 0) red[tid >> 6] = ss;
    __syncthreads();
    const float S = red[0] + red[1] + red[2] + red[3];

    const float inv = 1.0f / (S + 1e-13f);
    u16* o16 = (u16*)s;
    o16[tid]       = f2bf(p0 * inv);
    o16[tid + 256] = f2bf(p1 * inv);
}

extern "C" void kernel_launch(void* const* d_in, const int* in_sizes, int n_in,
                              void* d_out, int out_size, void* d_ws, size_t ws_size,
                              hipStream_t stream)
{
    (void)in_sizes; (void)n_in; (void)out_size; (void)ws_size;
    constexpr int B = 16, L = 512, H = 768;
    constexpr size_t NPQ = (size_t)B * L * H;   // 6291456
    constexpr size_t NW  = (size_t)H * H;       // 589824

    const float* proj_p  = (const float*)d_in[0];
    const float* proj_q  = (const float*)d_in[1];
    const int*   seq_len = (const int*)d_in[2];
    const float* W       = (const float*)d_in[3];
    const float* bias    = (const float*)d_in[4];
    float* out = (float*)d_out;

    // workspace (u16 elements)
    u16* ws   = (u16*)d_ws;
    u16* Ah   = ws;                 // pq split, then pp split; later att_vec bf16
    u16* Al   = Ah + NPQ;
    u16* Wh   = Al + NPQ;
    u16* Wl   = Wh + NW;
    u16* pqT  = Wl + NW;            // [B,768,512] bf16
    float* att = (float*)(pqT + NPQ);  // [B,512,512] fp32 -> probs bf16 in place
    u16* att_vec = Ah;              // alias (pp split dead after GEMM2)

    // trans_q hi/lo planes live in d_out (exactly fills it), dead before GEMM5 writes
    u16* tq_hi = (u16*)d_out;
    u16* tq_lo = tq_hi + NPQ;

    // 1) splits + transposed bf16 proj_q
    split_f32<<<576, 256, 0, stream>>>(W, Wh, Wl, (int)(NW / 4));
    split_f32<<<2048, 256, 0, stream>>>(proj_q, Ah, Al, (int)(NPQ / 4));
    transpose_to_bf16<<<dim3(24, 16, 16), dim3(32, 8), 0, stream>>>(proj_q, pqT);

    // 2) trans_q = pq @ W^T + bias  (split in, split out)
    gemm_nt<true, 2, true, false><<<dim3(6, 64, 1), 256, 0, stream>>>(
        Ah, Al, Wh, Wl, bias, tq_hi, tq_lo, H, H, H, H, 0, 0, 0);

    // 3) pp split (reuse Ah/Al)
    split_f32<<<2048, 256, 0, stream>>>(proj_p, Ah, Al, (int)(NPQ / 4));

    // 4) att[b] = pp[b] @ trans_q[b]^T  (split in, fp32 out)
    gemm_nt<true, 0, false, false><<<dim3(4, 4, 16), 256, 0, stream>>>(
        Ah, Al, tq_hi, tq_lo, nullptr, att, nullptr, H, H, H, L,
        (long)L * H, (long)L * H, (long)L * L);

    // 5) masked softmax, bf16 probs in place (lda = 1024 u16)
    softmax_kernel<<<B * L, 256, 0, stream>>>(att, seq_len);

    // 6) att_vec[b] = probs[b] @ pqT[b]^T  (bf16, bf16 out)
    gemm_nt<false, 1, false, false><<<dim3(6, 4, 16), 256, 0, stream>>>(
        (const u16*)att, nullptr, pqT, nullptr, nullptr, att_vec, nullptr,
        L, 1024, L, H, (long)L * 1024, (long)H * L, (long)L * H);

    // 7) out = relu(att_vec @ W^T + bias)  (bf16 in, fp32 out)
    gemm_nt<false, 0, true, true><<<dim3(6, 64, 1), 256, 0, stream>>>(
        att_vec, nullptr, Wh, nullptr, bias, out, nullptr, H, H, H, H, 0, 0, 0);
}